// Round 16
// baseline (289.382 us; speedup 1.0000x reference)
//
#include <hip/hip_runtime.h>
#include <hip/hip_bf16.h>

// ChildSum TreeLSTM, complete 4-ary tree. N=65536, D=300(->320), H=256, K=4.
// Internal [0,16384), leaves [16384,65536). Children of n: 4n+1..4n+4.
// Round 16: tail levels 1..7 fused into one kernel per level (block owns 32
// parents end-to-end: F-GEMM -> fc in LDS -> IU-GEMM (I/U col-interleaved
// per wave) -> gates + hsum). No grid barriers (R13 lesson). Level 0 keeps
// rec0/gate0. 11 dispatches. lp_gemm keeps R15's XCD swizzle (FETCH 4x win).

#define NTOT 65536
#define DD   300
#define KP   320
#define HH   256
#define LEAF_START 16384
#define LOG2E 1.4426950408889634f

typedef unsigned short u16;
typedef unsigned int   u32;
typedef __attribute__((ext_vector_type(8))) short bf16x8;
typedef __attribute__((ext_vector_type(4))) float f32x4;

union BF8 { bf16x8 v; u16 u[8]; };

// ---- ws layout (bytes) ----
#define OFF_HB    0ull                                   // [65537][256] bf16
#define OFF_CB    33554944ull                            // [65537][256] bf16
#define OFF_PRE   67109888ull                            // [16384][768] bf16
#define OFF_WXB   92275712ull                            // [768][320] bf16
#define OFF_WHB   92767232ull                            // [768][256] bf16
#define OFF_XB    93160448ull                            // [65536][320] bf16
#define OFF_PIU   135103488ull                           // [11008][512] bf16
#define OFF_FC    146375680ull                           // [11008][256] f32
#define OFF_HSB   157647872ull                           // [16512][256] bf16
#define OFF_BI    166102016ull                           // [256] f32
#define OFF_BU    166103040ull
#define OFF_BF    166104064ull

__device__ __forceinline__ float frcp(float x) { return __builtin_amdgcn_rcpf(x); }
__device__ __forceinline__ float fex2(float x) { return __builtin_amdgcn_exp2f(x); }
__device__ __forceinline__ float sigm(float x)  { return frcp(1.f + fex2(-LOG2E * x)); }
__device__ __forceinline__ float ftanh(float x) { return 1.f - 2.f * frcp(1.f + fex2(2.f * LOG2E * x)); }

__device__ __forceinline__ u16 f2bf(float f) {
    __hip_bfloat16 b = __float2bfloat16(f);
    u16 u; __builtin_memcpy(&u, &b, 2); return u;
}
__device__ __forceinline__ float bf2f(u16 b) {
    union { u32 u; float f; } v; v.u = ((u32)b) << 16;
    return v.f;
}
__device__ __forceinline__ int lidx(int r, int g) { return (r << 3) | (g ^ (r & 7)); }
__device__ __forceinline__ int lidx4(int r, int g) { return (r << 2) | (g ^ (r & 3)); }

__device__ __forceinline__ void gll16(const void* g, void* l) {
    __builtin_amdgcn_global_load_lds(
        (const __attribute__((address_space(1))) unsigned int*)g,
        (__attribute__((address_space(3))) unsigned int*)l, 16, 0, 0);
}

// ---- merged conversions: conv_x | conv_wx | conv_wh(+init) ----
__global__ __launch_bounds__(256) void conv_all(
    const float* __restrict__ X,
    const float* __restrict__ ixw, const float* __restrict__ uxw,
    const float* __restrict__ fiw,
    const float* __restrict__ ihw, const float* __restrict__ uhw,
    const float* __restrict__ fhw,
    const float* __restrict__ ixb, const float* __restrict__ ihb,
    const float* __restrict__ uxb, const float* __restrict__ uhb,
    const float* __restrict__ fib, const float* __restrict__ fhb,
    u32* __restrict__ Xb2, u32* __restrict__ Wxb2, u32* __restrict__ Whb2,
    u16* __restrict__ hb, u16* __restrict__ cb,
    float* __restrict__ bI, float* __restrict__ bU, float* __restrict__ bF)
{
    const int b = blockIdx.x;
    const int t = threadIdx.x;
    if (b < 2048) {                                      // X -> Xb
        const size_t total = (size_t)NTOT * 160;
        for (size_t id = (size_t)b * 256 + t; id < total; id += (size_t)2048 * 256) {
            const int node = (int)(id / 160);
            const int k    = ((int)(id % 160)) * 2;
            const float f0 = (k < DD)     ? X[(size_t)node * DD + k]     : 0.f;
            const float f1 = (k + 1 < DD) ? X[(size_t)node * DD + k + 1] : 0.f;
            Xb2[id] = (u32)f2bf(f0) | ((u32)f2bf(f1) << 16);
        }
    } else if (b < 2528) {                               // [ixw;uxw;fiw] -> Wxb
        const int b2 = b - 2048;
        const int total = 768 * 160;
        for (int id = b2 * 256 + t; id < total; id += 480 * 256) {
            const int row = id / 160;
            const int k   = (id % 160) * 2;
            const float* src = (row < 256) ? (ixw + (size_t)row * DD)
                             : (row < 512) ? (uxw + (size_t)(row - 256) * DD)
                                           : (fiw + (size_t)(row - 512) * DD);
            const float f0 = (k < DD)     ? src[k]     : 0.f;
            const float f1 = (k + 1 < DD) ? src[k + 1] : 0.f;
            Wxb2[id] = (u32)f2bf(f0) | ((u32)f2bf(f1) << 16);
        }
    } else {                                             // [ihw;uhw;fhw] -> Whb
        const int b3 = b - 2528;
        if (b3 == 0) {
            hb[(size_t)NTOT * HH + t] = 0;
            cb[(size_t)NTOT * HH + t] = 0;
            bI[t] = ixb[t] + ihb[t];
            bU[t] = uxb[t] + uhb[t];
            bF[t] = fib[t] + fhb[t];
        }
        const int total = 768 * 128;
        for (int id = b3 * 256 + t; id < total; id += 384 * 256) {
            const int row = id / 128;
            const int k   = (id % 128) * 2;
            const float* src = (row < 256) ? (ihw + (size_t)row * HH)
                             : (row < 512) ? (uhw + (size_t)(row - 256) * HH)
                                           : (fhw + (size_t)(row - 512) * HH);
            Whb2[id] = (u32)f2bf(src[k]) | ((u32)f2bf(src[k + 1]) << 16);
        }
    }
}

// ---- merged leaf + proj GEMM, 2-phase gll16 staging, XCD-swizzled blocks ----
__global__ __launch_bounds__(256) void lp_gemm(
    const u16* __restrict__ Xb, const u16* __restrict__ Wxb,
    const float* __restrict__ bI, const float* __restrict__ bU,
    u16* __restrict__ hb, u16* __restrict__ cb, u16* __restrict__ pre)
{
    __shared__ bf16x8 Ash[2048];
    __shared__ bf16x8 Bsh[2048];

    const int tid  = threadIdx.x;
    const int lane = tid & 63;
    const int w    = tid >> 6;
    const int wr   = w >> 1, wc = w & 1;
    const int m16  = lane & 15, q = lane >> 4;

    const bf16x8* __restrict__ Xv = (const bf16x8*)Xb;   // 40 granules/row
    const bf16x8* __restrict__ Wv = (const bf16x8*)Wxb;

    if (blockIdx.x < 1536) {
        // ---- leaf: 128 nodes x 64 ch, B-tile = [64 ix | 64 ux] ----
        const int xcd = blockIdx.x & 7, tt = blockIdx.x >> 3;
        const int c = tt & 3, rg = tt >> 2;
        const int row0   = LEAF_START + (rg * 8 + xcd) * 128;
        const int chbase = c * 64;

        auto stage = [&](int kt, int buf) {
            const int base = buf << 10;
            #pragma unroll
            for (int i = 0; i < 4; ++i) {
                const int sI = w * 256 + i * 64 + lane;
                const int r = sI >> 3, gs = sI & 7;
                const int g = gs ^ (r & 7);
                gll16(Xv + (size_t)(row0 + r) * 40 + kt * 8 + g, &Ash[base + sI]);
            }
            #pragma unroll
            for (int i = 0; i < 4; ++i) {
                const int sI = w * 256 + i * 64 + lane;
                const int br = sI >> 3, gs = sI & 7;
                const int g = gs ^ (br & 7);
                const int srow = ((br >> 6) << 8) + chbase + (br & 63);
                gll16(Wv + (size_t)srow * 40 + kt * 8 + g, &Bsh[base + sI]);
            }
        };

        f32x4 accI[4][2], accU[4][2];
        #pragma unroll
        for (int mf = 0; mf < 4; ++mf)
            #pragma unroll
            for (int nf = 0; nf < 2; ++nf) { accI[mf][nf] = (f32x4)0.f; accU[mf][nf] = (f32x4)0.f; }

        stage(0, 0);
        __syncthreads();
        for (int kt = 0; kt < 5; ++kt) {
            const int cur = kt & 1;
            if (kt < 4) stage(kt + 1, cur ^ 1);
            const int base = cur << 10;
            #pragma unroll
            for (int ks = 0; ks < 2; ++ks) {
                const int kg = ks * 4 + q;
                bf16x8 a[4], bIv[2], bUv[2];
                #pragma unroll
                for (int mf = 0; mf < 4; ++mf)
                    a[mf] = Ash[base + lidx(wr * 64 + mf * 16 + m16, kg)];
                #pragma unroll
                for (int nf = 0; nf < 2; ++nf) {
                    bIv[nf] = Bsh[base + lidx(wc * 32 + nf * 16 + m16, kg)];
                    bUv[nf] = Bsh[base + lidx(64 + wc * 32 + nf * 16 + m16, kg)];
                }
                #pragma unroll
                for (int mf = 0; mf < 4; ++mf)
                    #pragma unroll
                    for (int nf = 0; nf < 2; ++nf) {
                        accI[mf][nf] = __builtin_amdgcn_mfma_f32_16x16x32_bf16(
                            a[mf], bIv[nf], accI[mf][nf], 0, 0, 0);
                        accU[mf][nf] = __builtin_amdgcn_mfma_f32_16x16x32_bf16(
                            a[mf], bUv[nf], accU[mf][nf], 0, 0, 0);
                    }
            }
            __syncthreads();
        }

        #pragma unroll
        for (int nf = 0; nf < 2; ++nf) {
            const int ch = chbase + wc * 32 + nf * 16 + m16;
            const float bi = bI[ch];           // recurrent biases apply at leaves
            const float bu = bU[ch];
            #pragma unroll
            for (int mf = 0; mf < 4; ++mf) {
                #pragma unroll
                for (int r4 = 0; r4 < 4; ++r4) {
                    const float cn = sigm(accI[mf][nf][r4] + bi) * ftanh(accU[mf][nf][r4] + bu);
                    const int node = row0 + wr * 64 + mf * 16 + q * 4 + r4;
                    const size_t off = (size_t)node * HH + ch;
                    cb[off] = f2bf(cn);
                    hb[off] = f2bf(ftanh(cn));
                }
            }
        }
    } else {
        // ---- proj: [16384 x 320] x [320 x 768] -> pre ----
        const int B2 = blockIdx.x - 1536;
        const int xcd = B2 & 7, tt = B2 >> 3;
        const int c = tt % 6, rg = tt / 6;
        const int row0 = (rg * 8 + xcd) * 128;
        const int n0   = c * 128;

        auto stage = [&](int kt, int buf) {
            const int base = buf << 10;
            #pragma unroll
            for (int i = 0; i < 4; ++i) {
                const int sI = w * 256 + i * 64 + lane;
                const int r = sI >> 3, gs = sI & 7;
                const int g = gs ^ (r & 7);
                gll16(Xv + (size_t)(row0 + r) * 40 + kt * 8 + g, &Ash[base + sI]);
            }
            #pragma unroll
            for (int i = 0; i < 4; ++i) {
                const int sI = w * 256 + i * 64 + lane;
                const int br = sI >> 3, gs = sI & 7;
                const int g = gs ^ (br & 7);
                gll16(Wv + (size_t)(n0 + br) * 40 + kt * 8 + g, &Bsh[base + sI]);
            }
        };

        f32x4 acc[4][4];
        #pragma unroll
        for (int mf = 0; mf < 4; ++mf)
            #pragma unroll
            for (int nf = 0; nf < 4; ++nf) acc[mf][nf] = (f32x4)0.f;

        stage(0, 0);
        __syncthreads();
        for (int kt = 0; kt < 5; ++kt) {
            const int cur = kt & 1;
            if (kt < 4) stage(kt + 1, cur ^ 1);
            const int base = cur << 10;
            #pragma unroll
            for (int ks = 0; ks < 2; ++ks) {
                const int kg = ks * 4 + q;
                bf16x8 a[4], b[4];
                #pragma unroll
                for (int mf = 0; mf < 4; ++mf)
                    a[mf] = Ash[base + lidx(wr * 64 + mf * 16 + m16, kg)];
                #pragma unroll
                for (int nf = 0; nf < 4; ++nf)
                    b[nf] = Bsh[base + lidx(wc * 64 + nf * 16 + m16, kg)];
                #pragma unroll
                for (int mf = 0; mf < 4; ++mf)
                    #pragma unroll
                    for (int nf = 0; nf < 4; ++nf)
                        acc[mf][nf] = __builtin_amdgcn_mfma_f32_16x16x32_bf16(
                            a[mf], b[nf], acc[mf][nf], 0, 0, 0);
            }
            __syncthreads();
        }

        #pragma unroll
        for (int mf = 0; mf < 4; ++mf)
            #pragma unroll
            for (int nf = 0; nf < 4; ++nf) {
                const int col = n0 + wc * 64 + nf * 16 + m16;
                #pragma unroll
                for (int r4 = 0; r4 < 4; ++r4) {
                    const int node = row0 + wr * 64 + mf * 16 + q * 4 + r4;
                    pre[(size_t)node * 768 + col] = f2bf(acc[mf][nf][r4]);
                }
            }
    }
}

// ---- level-0 recurrent GEMM (unchanged from R15) ----
__global__ __launch_bounds__(256) void rec_gemm(
    const u16* __restrict__ hb, const u16* __restrict__ hsb,
    const u16* __restrict__ Whb, const u16* __restrict__ pre,
    const float* __restrict__ bF, const u16* __restrict__ cb,
    u16* __restrict__ projIU, float* __restrict__ fcbuf,
    int s, int crow0, int L, int bigIU)
{
    __shared__ bf16x8 Ash[2048];
    __shared__ bf16x8 Bsh[2048];

    const int nIUrb = (L + 127) >> 7;
    const int bid   = blockIdx.x;

    bool isIU; int rb, cbk;
    if (bid < nIUrb * 4) { isIU = true;  rb = bid >> 2; cbk = bid & 3; }
    else { isIU = false; const int b2 = bid - nIUrb * 4; rb = b2 >> 1; cbk = b2 & 1; }

    const int row0  = rb * 128;
    const int Brow0 = isIU ? cbk * 128 : 512 + cbk * 128;
    const int ocol0 = cbk * 128;

    const int tid  = threadIdx.x;
    const int lane = tid & 63;
    const int w    = tid >> 6;
    const int wr   = w >> 1, wc = w & 1;
    const int m16  = lane & 15, q = lane >> 4;

    const bf16x8* __restrict__ Hv = (const bf16x8*)hb;
    const bf16x8* __restrict__ Sv = (const bf16x8*)hsb;
    const bf16x8* __restrict__ Wv = (const bf16x8*)Whb;

    auto stage = [&](int kt, int buf) {
        const int base = buf << 10;
        if (isIU && bigIU) {
            #pragma unroll
            for (int i = 0; i < 4; ++i) {
                const int G = tid + i * 256;
                const int r = G >> 3, g = G & 7;
                bf16x8 val;
                if (row0 + r < L) {
                    const size_t cg0 = (size_t)(crow0 + 4 * (row0 + r)) * 32 + kt * 8 + g;
                    BF8 x0, x1, x2, x3, o;
                    x0.v = Hv[cg0]; x1.v = Hv[cg0 + 32];
                    x2.v = Hv[cg0 + 64]; x3.v = Hv[cg0 + 96];
                    #pragma unroll
                    for (int j = 0; j < 8; ++j)
                        o.u[j] = f2bf(bf2f(x0.u[j]) + bf2f(x1.u[j])
                                    + bf2f(x2.u[j]) + bf2f(x3.u[j]));
                    val = o.v;
                } else {
                    BF8 z;
                    #pragma unroll
                    for (int j = 0; j < 8; ++j) z.u[j] = 0;
                    val = z.v;
                }
                Ash[base + lidx(r, g)] = val;
            }
        } else {
            #pragma unroll
            for (int i = 0; i < 4; ++i) {
                const int sI = w * 256 + i * 64 + lane;
                const int r = sI >> 3, gs = sI & 7;
                const int g = gs ^ (r & 7);
                if (isIU) {
                    gll16(Sv + (size_t)(s + row0 + r) * 32 + kt * 8 + g, &Ash[base + sI]);
                } else {
                    int arow = crow0 + row0 + r;
                    if (arow > NTOT) arow = NTOT;
                    gll16(Hv + (size_t)arow * 32 + kt * 8 + g, &Ash[base + sI]);
                }
            }
        }
        #pragma unroll
        for (int i = 0; i < 4; ++i) {
            const int sI = w * 256 + i * 64 + lane;
            const int br = sI >> 3, gs = sI & 7;
            const int g = gs ^ (br & 7);
            gll16(Wv + (size_t)(Brow0 + br) * 32 + kt * 8 + g, &Bsh[base + sI]);
        }
    };

    f32x4 acc[4][4];
    #pragma unroll
    for (int mf = 0; mf < 4; ++mf)
        #pragma unroll
        for (int nf = 0; nf < 4; ++nf) acc[mf][nf] = (f32x4)0.f;

    stage(0, 0);
    __syncthreads();
    for (int kt = 0; kt < 4; ++kt) {
        const int cur = kt & 1;
        if (kt < 3) stage(kt + 1, cur ^ 1);
        const int base = cur << 10;
        #pragma unroll
        for (int ks = 0; ks < 2; ++ks) {
            const int kg = ks * 4 + q;
            bf16x8 a[4], b[4];
            #pragma unroll
            for (int mf = 0; mf < 4; ++mf)
                a[mf] = Ash[base + lidx(wr * 64 + mf * 16 + m16, kg)];
            #pragma unroll
            for (int nf = 0; nf < 4; ++nf)
                b[nf] = Bsh[base + lidx(wc * 64 + nf * 16 + m16, kg)];
            #pragma unroll
            for (int mf = 0; mf < 4; ++mf)
                #pragma unroll
                for (int nf = 0; nf < 4; ++nf)
                    acc[mf][nf] = __builtin_amdgcn_mfma_f32_16x16x32_bf16(
                        a[mf], b[nf], acc[mf][nf], 0, 0, 0);
        }
        __syncthreads();
    }

    if (isIU) {
        #pragma unroll
        for (int mf = 0; mf < 4; ++mf)
            #pragma unroll
            for (int nf = 0; nf < 4; ++nf) {
                const int col = ocol0 + wc * 64 + nf * 16 + m16;
                #pragma unroll
                for (int r4 = 0; r4 < 4; ++r4) {
                    const int orow = row0 + wr * 64 + mf * 16 + q * 4 + r4;
                    projIU[(size_t)orow * 512 + col] = f2bf(acc[mf][nf][r4]);
                }
            }
    } else {
        #pragma unroll
        for (int mf = 0; mf < 4; ++mf) {
            const int off  = wr * 64 + mf * 16 + q * 4;
            const int goff = (row0 + off) >> 2;
            if (goff < L) {
                #pragma unroll
                for (int nf = 0; nf < 4; ++nf) {
                    const int col = ocol0 + wc * 64 + nf * 16 + m16;
                    const float fpre = bf2f(pre[(size_t)(s + goff) * 768 + 512 + col]) + bF[col];
                    float fc = 0.f;
                    #pragma unroll
                    for (int r4 = 0; r4 < 4; ++r4) {
                        int child = crow0 + row0 + off + r4;
                        if (child > NTOT) child = NTOT;
                        const float cc = bf2f(cb[(size_t)child * HH + col]);
                        fc = fmaf(sigm(acc[mf][nf][r4] + fpre), cc, fc);
                    }
                    fcbuf[(size_t)goff * HH + col] = fc;
                }
            }
        }
    }
}

// ---- level-0 gates (+ hsum_small partition) — unchanged from R15 ----
__global__ __launch_bounds__(256) void gate_kernel(
    const u32* __restrict__ pre2, const u32* __restrict__ pIU2,
    const float* __restrict__ fcbuf,
    const float* __restrict__ bI, const float* __restrict__ bU,
    u32* __restrict__ hb2, u32* __restrict__ cb2, u32* __restrict__ hsumb2,
    float* __restrict__ out, int s, int L)
{
    const int t  = threadIdx.x;
    const int j2 = t & 127;

    const int ng = (L + 3) >> 2;
    const int gateBlocks = (ng + 1) >> 1;
    if ((int)blockIdx.x >= gateBlocks) {
        const int id = ((int)blockIdx.x - gateBlocks) * 256 + t;
        if (id < 1365 * 128) {
            const int ploc = id >> 7, jj = id & 127;
            const int p = 4096 + ploc;
            const int c0 = 4 * p + 1;
            float s0 = 0.f, s1 = 0.f;
            #pragma unroll
            for (int k = 0; k < 4; ++k) {
                const u32 v = hb2[(size_t)(c0 + k) * 128 + jj];
                s0 += bf2f((u16)v);
                s1 += bf2f((u16)(v >> 16));
            }
            hsumb2[(size_t)p * 128 + jj] = (u32)f2bf(s0) | ((u32)f2bf(s1) << 16);
        }
        return;
    }

    const float2 vbi = ((const float2*)bI)[j2];
    const float2 vbu = ((const float2*)bU)[j2];
    const int g = blockIdx.x * 2 + (t >> 7);
    if (g >= ng) return;
    const int p = ((s - 1) >> 2) + g;

    float hs0 = 0.f, hs1 = 0.f;
    #pragma unroll
    for (int k = 0; k < 4; ++k) {
        const int nloc = 4 * g + k;
        const int n = s + nloc;
        if (nloc < L) {
            const u32 pi = pre2[(size_t)n * 384 + j2];
            const u32 pu = pre2[(size_t)n * 384 + 128 + j2];
            const u32 ri = pIU2[(size_t)nloc * 256 + j2];
            const u32 ru = pIU2[(size_t)nloc * 256 + 128 + j2];
            const float aI0 = bf2f((u16)pi) + bf2f((u16)ri) + vbi.x;
            const float aI1 = bf2f((u16)(pi >> 16)) + bf2f((u16)(ri >> 16)) + vbi.y;
            const float aU0 = bf2f((u16)pu) + bf2f((u16)ru) + vbu.x;
            const float aU1 = bf2f((u16)(pu >> 16)) + bf2f((u16)(ru >> 16)) + vbu.y;
            const float2 fc = ((const float2*)fcbuf)[(size_t)nloc * 128 + j2];
            const float cn0 = fmaf(sigm(aI0), ftanh(aU0), fc.x);
            const float cn1 = fmaf(sigm(aI1), ftanh(aU1), fc.y);
            const float hn0 = ftanh(cn0);
            const float hn1 = ftanh(cn1);
            hb2[(size_t)n * 128 + j2] = (u32)f2bf(hn0) | ((u32)f2bf(hn1) << 16);
            cb2[(size_t)n * 128 + j2] = (u32)f2bf(cn0) | ((u32)f2bf(cn1) << 16);
            hs0 += hn0; hs1 += hn1;
        } else {
            const u32 v = hb2[(size_t)n * 128 + j2];
            hs0 += bf2f((u16)v);
            hs1 += bf2f((u16)(v >> 16));
        }
    }
    hsumb2[(size_t)p * 128 + j2] = (u32)f2bf(hs0) | ((u32)f2bf(hs1) << 16);
}

// ---- fused tail level: block owns 32 parents end-to-end ----
// Phase F: child GEMM (128 children x 256 F-cols), fc -> LDS.
// Phase IU: hsum GEMM (32 x 512), I/U col-interleaved per wave.
// Phase G: gates in-register, write h/c/hsum.
__global__ __launch_bounds__(256) void level_kernel(
    u16* __restrict__ hb, u16* __restrict__ cb, u16* __restrict__ hsb,
    const u16* __restrict__ Whb, const u16* __restrict__ pre,
    const float* __restrict__ bI, const float* __restrict__ bU,
    const float* __restrict__ bF,
    float* __restrict__ out, int s, int crow0, int L)
{
    __shared__ float  fcs[32 * 256];   // 32 KB
    __shared__ bf16x8 Abuf[512];       // 8 KB (child-A / hsum-A chunks)
    __shared__ bf16x8 Bbuf[1024];      // 16 KB (Whb row chunks)

    const int tid  = threadIdx.x;
    const int lane = tid & 63;
    const int w    = tid >> 6;
    const int m16  = lane & 15, q = lane >> 4;
    const int b    = blockIdx.x;
    const int p0   = 32 * b;

    const bf16x8* __restrict__ Hv = (const bf16x8*)hb;   // 32 granules/row
    const bf16x8* __restrict__ Sv = (const bf16x8*)hsb;
    const bf16x8* __restrict__ Wv = (const bf16x8*)Whb;

    // ---------------- Phase F ----------------
    f32x4 accF[8][4];
    #pragma unroll
    for (int mf = 0; mf < 8; ++mf)
        #pragma unroll
        for (int nf = 0; nf < 4; ++nf) accF[mf][nf] = (f32x4)0.f;

    for (int kt = 0; kt < 8; ++kt) {                     // K-chunk 32 (4 granules)
        __syncthreads();
        #pragma unroll
        for (int i = 0; i < 2; ++i) {                    // A: 128 rows x 4 gran
            const int sI = w * 128 + i * 64 + lane;
            const int r = sI >> 2, gs = sI & 3;
            const int g = gs ^ (r & 3);
            int child = crow0 + 128 * b + r;
            if (child > NTOT) child = NTOT;              // zeroed pad row
            gll16(Hv + (size_t)child * 32 + kt * 4 + g, &Abuf[sI]);
        }
        #pragma unroll
        for (int i = 0; i < 4; ++i) {                    // B: Whb rows 512..767
            const int sI = w * 256 + i * 64 + lane;
            const int r = sI >> 2, gs = sI & 3;
            const int g = gs ^ (r & 3);
            gll16(Wv + (size_t)(512 + r) * 32 + kt * 4 + g, &Bbuf[sI]);
        }
        __syncthreads();
        bf16x8 a[8], bb[4];
        #pragma unroll
        for (int mf = 0; mf < 8; ++mf) {
            const int R = mf * 16 + m16;
            a[mf] = Abuf[lidx4(R, q)];
        }
        #pragma unroll
        for (int nf = 0; nf < 4; ++nf) {
            const int R = 64 * w + nf * 16 + m16;
            bb[nf] = Bbuf[lidx4(R, q)];
        }
        #pragma unroll
        for (int mf = 0; mf < 8; ++mf)
            #pragma unroll
            for (int nf = 0; nf < 4; ++nf)
                accF[mf][nf] = __builtin_amdgcn_mfma_f32_16x16x32_bf16(
                    a[mf], bb[nf], accF[mf][nf], 0, 0, 0);
    }
    __syncthreads();

    // F epilogue: fc per (parent, col) -> LDS
    #pragma unroll
    for (int mf = 0; mf < 8; ++mf) {
        const int par = mf * 4 + q;                      // 0..31
        if (p0 + par < L) {
            const int chrow = mf * 16 + q * 4;           // sibling-group base row
            #pragma unroll
            for (int nf = 0; nf < 4; ++nf) {
                const int col = 64 * w + nf * 16 + m16;
                const float fpre = bf2f(pre[(size_t)(s + p0 + par) * 768 + 512 + col]) + bF[col];
                float fc = 0.f;
                #pragma unroll
                for (int r4 = 0; r4 < 4; ++r4) {
                    int child = crow0 + 128 * b + chrow + r4;
                    if (child > NTOT) child = NTOT;
                    const float cc = bf2f(cb[(size_t)child * HH + col]);
                    fc = fmaf(sigm(accF[mf][nf][r4] + fpre), cc, fc);
                }
                fcs[par * 256 + col] = fc;
            }
        }
    }

    // ---------------- Phase IU ----------------
    f32x4 accIU[2][8];
    #pragma unroll
    for (int mf = 0; mf < 2; ++mf)
        #pragma unroll
        for (int nf = 0; nf < 8; ++nf) accIU[mf][nf] = (f32x4)0.f;

    for (int kt = 0; kt < 8; ++kt) {
        __syncthreads();
        if (lane < 32) {                                 // A: 32 hsum rows x 4 gran
            const int sI = w * 32 + lane;
            const int r = sI >> 2, gs = sI & 3;
            const int g = gs ^ (r & 3);
            gll16(Sv + (size_t)(s + p0 + r) * 32 + kt * 4 + g, &Abuf[sI]);
        }
        #pragma unroll
        for (int i = 0; i < 4; ++i) {                    // B-I: Whb rows 0..255
            const int sI = w * 256 + i * 64 + lane;
            const int r = sI >> 2, gs = sI & 3;
            const int g = gs ^ (r & 3);
            gll16(Wv + (size_t)r * 32 + kt * 4 + g, &Bbuf[sI]);
        }
        __syncthreads();
        bf16x8 a2[2], b2[4];
        #pragma unroll
        for (int mf = 0; mf < 2; ++mf) {
            const int R = mf * 16 + m16;
            a2[mf] = Abuf[lidx4(R, q)];
        }
        #pragma unroll
        for (int nf = 0; nf < 4; ++nf) {
            const int R = 64 * w + nf * 16 + m16;
            b2[nf] = Bbuf[lidx4(R, q)];
        }
        #pragma unroll
        for (int mf = 0; mf < 2; ++mf)
            #pragma unroll
            for (int nf = 0; nf < 4; ++nf)
                accIU[mf][nf] = __builtin_amdgcn_mfma_f32_16x16x32_bf16(
                    a2[mf], b2[nf], accIU[mf][nf], 0, 0, 0);
        __syncthreads();
        #pragma unroll
        for (int i = 0; i < 4; ++i) {                    // B-U: Whb rows 256..511
            const int sI = w * 256 + i * 64 + lane;
            const int r = sI >> 2, gs = sI & 3;
            const int g = gs ^ (r & 3);
            gll16(Wv + (size_t)(256 + r) * 32 + kt * 4 + g, &Bbuf[sI]);
        }
        __syncthreads();
        #pragma unroll
        for (int nf = 0; nf < 4; ++nf) {
            const int R = 64 * w + nf * 16 + m16;
            b2[nf] = Bbuf[lidx4(R, q)];
        }
        #pragma unroll
        for (int mf = 0; mf < 2; ++mf)
            #pragma unroll
            for (int nf = 0; nf < 4; ++nf)
                accIU[mf][nf + 4] = __builtin_amdgcn_mfma_f32_16x16x32_bf16(
                    a2[mf], b2[nf], accIU[mf][nf + 4], 0, 0, 0);
    }
    __syncthreads();

    // ---------------- Phase G: gates ----------------
    #pragma unroll
    for (int mf2 = 0; mf2 < 2; ++mf2) {
        #pragma unroll
        for (int nf = 0; nf < 4; ++nf) {
            const int c = 64 * w + nf * 16 + m16;
            float hs = 0.f;
            #pragma unroll
            for (int r4 = 0; r4 < 4; ++r4) {
                const int p = mf2 * 16 + q * 4 + r4;
                const int n = s + p0 + p;
                float hn;
                if (p0 + p < L) {
                    const float aI = accIU[mf2][nf][r4]
                                   + bf2f(pre[(size_t)n * 768 + c]) + bI[c];
                    const float aU = accIU[mf2][nf + 4][r4]
                                   + bf2f(pre[(size_t)n * 768 + 256 + c]) + bU[c];
                    const float cn = fmaf(sigm(aI), ftanh(aU), fcs[p * 256 + c]);
                    hn = ftanh(cn);
                    hb[(size_t)n * HH + c] = f2bf(hn);
                    cb[(size_t)n * HH + c] = f2bf(cn);
                    if (n == 0) { out[c] = hn; out[256 + c] = cn; }
                } else {
                    hn = bf2f(hb[(size_t)n * HH + c]);   // beyond-level sibling
                }
                hs += hn;
            }
            const int base = mf2 * 16 + q * 4;
            if (p0 + base < L) {
                const int gp = ((s - 1) >> 2) + ((p0 + base) >> 2);
                hsb[(size_t)gp * HH + c] = f2bf(hs);
            }
        }
    }
}

extern "C" void kernel_launch(void* const* d_in, const int* in_sizes, int n_in,
                              void* d_out, int out_size, void* d_ws, size_t ws_size,
                              hipStream_t stream) {
    const float* X   = (const float*)d_in[0];
    const float* ixw = (const float*)d_in[1];
    const float* ixb = (const float*)d_in[2];
    const float* ihw = (const float*)d_in[3];
    const float* ihb = (const float*)d_in[4];
    const float* uxw = (const float*)d_in[5];
    const float* uxb = (const float*)d_in[6];
    const float* uhw = (const float*)d_in[7];
    const float* uhb = (const float*)d_in[8];
    const float* fiw = (const float*)d_in[9];
    const float* fib = (const float*)d_in[10];
    const float* fhw = (const float*)d_in[11];
    const float* fhb = (const float*)d_in[12];
    float* out = (float*)d_out;

    char* ws = (char*)d_ws;
    u16* hb   = (u16*)(ws + OFF_HB);
    u16* cb   = (u16*)(ws + OFF_CB);
    u16* pre  = (u16*)(ws + OFF_PRE);
    u16* Wxb  = (u16*)(ws + OFF_WXB);
    u16* Whb  = (u16*)(ws + OFF_WHB);
    u16* Xb   = (u16*)(ws + OFF_XB);
    u16* pIU  = (u16*)(ws + OFF_PIU);
    float* fc = (float*)(ws + OFF_FC);
    u16* hsb  = (u16*)(ws + OFF_HSB);
    float* bI = (float*)(ws + OFF_BI);
    float* bU = (float*)(ws + OFF_BU);
    float* bF = (float*)(ws + OFF_BF);

    conv_all<<<2912, 256, 0, stream>>>(X, ixw, uxw, fiw, ihw, uhw, fhw,
        ixb, ihb, uxb, uhb, fib, fhb,
        (u32*)Xb, (u32*)Wxb, (u32*)Whb, hb, cb, bI, bU, bF);

    lp_gemm<<<2304, 256, 0, stream>>>(Xb, Wxb, bI, bU, hb, cb, pre);

    // level 0 (L=10923): proven rec0 + gate0 pair
    {
        const int s = 5461, L = 10923, crow0 = 21845;
        const int nIUrb = (L + 127) >> 7;
        const int nFrb  = (4 * L + 127) >> 7;
        rec_gemm<<<nIUrb * 4 + nFrb * 2, 256, 0, stream>>>(hb, hsb, Whb, pre, bF, cb,
            pIU, fc, s, crow0, L, 1);
        const int ng = (L + 3) >> 2;
        const int gateBlocks = (ng + 1) >> 1;
        gate_kernel<<<gateBlocks + 683, 256, 0, stream>>>(
            (const u32*)pre, (const u32*)pIU, fc, bI, bU,
            (u32*)hb, (u32*)cb, (u32*)hsb, out, s, L);
    }

    // levels 1..7: fused rec+gate, one launch per level
    const int starts[7] = {1365, 341, 85, 21, 5, 1, 0};
    const int Ls[7]     = {4096, 1024, 256, 64, 16, 4, 1};
    for (int l = 0; l < 7; ++l) {
        const int s = starts[l], L = Ls[l];
        const int crow0 = 4 * s + 1;
        const int nPB = (L + 31) >> 5;
        level_kernel<<<nPB, 256, 0, stream>>>(hb, cb, hsb, Whb, pre,
                                              bI, bU, bF, out, s, crow0, L);
    }
}

// Round 17
// 189.767 us; speedup vs baseline: 1.5249x; 1.5249x over previous
//
#include <hip/hip_runtime.h>
#include <hip/hip_bf16.h>

// ChildSum TreeLSTM, complete 4-ary tree. N=65536, D=300(->320), H=256, K=4.
// Internal [0,16384), leaves [16384,65536). Children of n: 4n+1..4n+4.
// Round 17: R15 structure (best: 186.6us). R16's fused tail reverted (serial
// syncs + idle CUs). New: lp_gemm epilogue stores via LDS-stage + coalesced
// u32 copy-out (was 64 scalar u16 stores/thread -> scattered 2B transactions).

#define NTOT 65536
#define DD   300
#define KP   320
#define HH   256
#define LEAF_START 16384
#define LOG2E 1.4426950408889634f

typedef unsigned short u16;
typedef unsigned int   u32;
typedef __attribute__((ext_vector_type(8))) short bf16x8;
typedef __attribute__((ext_vector_type(4))) float f32x4;

union BF8 { bf16x8 v; u16 u[8]; };

// ---- ws layout (bytes) ----
#define OFF_HB    0ull                                   // [65537][256] bf16
#define OFF_CB    33554944ull                            // [65537][256] bf16
#define OFF_PRE   67109888ull                            // [16384][768] bf16
#define OFF_WXB   92275712ull                            // [768][320] bf16
#define OFF_WHB   92767232ull                            // [768][256] bf16
#define OFF_XB    93160448ull                            // [65536][320] bf16
#define OFF_PIU   135103488ull                           // [11008][512] bf16
#define OFF_FC    146375680ull                           // [11008][256] f32
#define OFF_HSB   157647872ull                           // [16512][256] bf16
#define OFF_BI    166102016ull                           // [256] f32
#define OFF_BU    166103040ull
#define OFF_BF    166104064ull

__device__ __forceinline__ float frcp(float x) { return __builtin_amdgcn_rcpf(x); }
__device__ __forceinline__ float fex2(float x) { return __builtin_amdgcn_exp2f(x); }
__device__ __forceinline__ float sigm(float x)  { return frcp(1.f + fex2(-LOG2E * x)); }
__device__ __forceinline__ float ftanh(float x) { return 1.f - 2.f * frcp(1.f + fex2(2.f * LOG2E * x)); }

__device__ __forceinline__ u16 f2bf(float f) {
    __hip_bfloat16 b = __float2bfloat16(f);
    u16 u; __builtin_memcpy(&u, &b, 2); return u;
}
__device__ __forceinline__ float bf2f(u16 b) {
    union { u32 u; float f; } v; v.u = ((u32)b) << 16;
    return v.f;
}
__device__ __forceinline__ int lidx(int r, int g) { return (r << 3) | (g ^ (r & 7)); }

__device__ __forceinline__ void gll16(const void* g, void* l) {
    __builtin_amdgcn_global_load_lds(
        (const __attribute__((address_space(1))) unsigned int*)g,
        (__attribute__((address_space(3))) unsigned int*)l, 16, 0, 0);
}

// ---- merged conversions: conv_x | conv_wx | conv_wh(+init) ----
__global__ __launch_bounds__(256) void conv_all(
    const float* __restrict__ X,
    const float* __restrict__ ixw, const float* __restrict__ uxw,
    const float* __restrict__ fiw,
    const float* __restrict__ ihw, const float* __restrict__ uhw,
    const float* __restrict__ fhw,
    const float* __restrict__ ixb, const float* __restrict__ ihb,
    const float* __restrict__ uxb, const float* __restrict__ uhb,
    const float* __restrict__ fib, const float* __restrict__ fhb,
    u32* __restrict__ Xb2, u32* __restrict__ Wxb2, u32* __restrict__ Whb2,
    u16* __restrict__ hb, u16* __restrict__ cb,
    float* __restrict__ bI, float* __restrict__ bU, float* __restrict__ bF)
{
    const int b = blockIdx.x;
    const int t = threadIdx.x;
    if (b < 2048) {                                      // X -> Xb
        const size_t total = (size_t)NTOT * 160;
        for (size_t id = (size_t)b * 256 + t; id < total; id += (size_t)2048 * 256) {
            const int node = (int)(id / 160);
            const int k    = ((int)(id % 160)) * 2;
            const float f0 = (k < DD)     ? X[(size_t)node * DD + k]     : 0.f;
            const float f1 = (k + 1 < DD) ? X[(size_t)node * DD + k + 1] : 0.f;
            Xb2[id] = (u32)f2bf(f0) | ((u32)f2bf(f1) << 16);
        }
    } else if (b < 2528) {                               // [ixw;uxw;fiw] -> Wxb
        const int b2 = b - 2048;
        const int total = 768 * 160;
        for (int id = b2 * 256 + t; id < total; id += 480 * 256) {
            const int row = id / 160;
            const int k   = (id % 160) * 2;
            const float* src = (row < 256) ? (ixw + (size_t)row * DD)
                             : (row < 512) ? (uxw + (size_t)(row - 256) * DD)
                                           : (fiw + (size_t)(row - 512) * DD);
            const float f0 = (k < DD)     ? src[k]     : 0.f;
            const float f1 = (k + 1 < DD) ? src[k + 1] : 0.f;
            Wxb2[id] = (u32)f2bf(f0) | ((u32)f2bf(f1) << 16);
        }
    } else {                                             // [ihw;uhw;fhw] -> Whb
        const int b3 = b - 2528;
        if (b3 == 0) {
            hb[(size_t)NTOT * HH + t] = 0;
            cb[(size_t)NTOT * HH + t] = 0;
            bI[t] = ixb[t] + ihb[t];
            bU[t] = uxb[t] + uhb[t];
            bF[t] = fib[t] + fhb[t];
        }
        const int total = 768 * 128;
        for (int id = b3 * 256 + t; id < total; id += 384 * 256) {
            const int row = id / 128;
            const int k   = (id % 128) * 2;
            const float* src = (row < 256) ? (ihw + (size_t)row * HH)
                             : (row < 512) ? (uhw + (size_t)(row - 256) * HH)
                                           : (fhw + (size_t)(row - 512) * HH);
            Whb2[id] = (u32)f2bf(src[k]) | ((u32)f2bf(src[k + 1]) << 16);
        }
    }
}

// ---- merged leaf + proj GEMM, 2-phase gll16 staging, XCD-swizzled blocks,
//      LDS-staged coalesced epilogue stores ----
__global__ __launch_bounds__(256) void lp_gemm(
    const u16* __restrict__ Xb, const u16* __restrict__ Wxb,
    const float* __restrict__ bI, const float* __restrict__ bU,
    u16* __restrict__ hb, u16* __restrict__ cb, u16* __restrict__ pre)
{
    __shared__ bf16x8 Ash[2048];
    __shared__ bf16x8 Bsh[2048];

    const int tid  = threadIdx.x;
    const int lane = tid & 63;
    const int w    = tid >> 6;
    const int wr   = w >> 1, wc = w & 1;
    const int m16  = lane & 15, q = lane >> 4;

    const bf16x8* __restrict__ Xv = (const bf16x8*)Xb;   // 40 granules/row
    const bf16x8* __restrict__ Wv = (const bf16x8*)Wxb;

    if (blockIdx.x < 1536) {
        // ---- leaf: 128 nodes x 64 ch, B-tile = [64 ix | 64 ux] ----
        const int xcd = blockIdx.x & 7, tt = blockIdx.x >> 3;
        const int c = tt & 3, rg = tt >> 2;
        const int row0   = LEAF_START + (rg * 8 + xcd) * 128;
        const int chbase = c * 64;

        auto stage = [&](int kt, int buf) {
            const int base = buf << 10;
            #pragma unroll
            for (int i = 0; i < 4; ++i) {
                const int sI = w * 256 + i * 64 + lane;
                const int r = sI >> 3, gs = sI & 7;
                const int g = gs ^ (r & 7);
                gll16(Xv + (size_t)(row0 + r) * 40 + kt * 8 + g, &Ash[base + sI]);
            }
            #pragma unroll
            for (int i = 0; i < 4; ++i) {
                const int sI = w * 256 + i * 64 + lane;
                const int br = sI >> 3, gs = sI & 7;
                const int g = gs ^ (br & 7);
                const int srow = ((br >> 6) << 8) + chbase + (br & 63);
                gll16(Wv + (size_t)srow * 40 + kt * 8 + g, &Bsh[base + sI]);
            }
        };

        f32x4 accI[4][2], accU[4][2];
        #pragma unroll
        for (int mf = 0; mf < 4; ++mf)
            #pragma unroll
            for (int nf = 0; nf < 2; ++nf) { accI[mf][nf] = (f32x4)0.f; accU[mf][nf] = (f32x4)0.f; }

        stage(0, 0);
        __syncthreads();
        for (int kt = 0; kt < 5; ++kt) {
            const int cur = kt & 1;
            if (kt < 4) stage(kt + 1, cur ^ 1);
            const int base = cur << 10;
            #pragma unroll
            for (int ks = 0; ks < 2; ++ks) {
                const int kg = ks * 4 + q;
                bf16x8 a[4], bIv[2], bUv[2];
                #pragma unroll
                for (int mf = 0; mf < 4; ++mf)
                    a[mf] = Ash[base + lidx(wr * 64 + mf * 16 + m16, kg)];
                #pragma unroll
                for (int nf = 0; nf < 2; ++nf) {
                    bIv[nf] = Bsh[base + lidx(wc * 32 + nf * 16 + m16, kg)];
                    bUv[nf] = Bsh[base + lidx(64 + wc * 32 + nf * 16 + m16, kg)];
                }
                #pragma unroll
                for (int mf = 0; mf < 4; ++mf)
                    #pragma unroll
                    for (int nf = 0; nf < 2; ++nf) {
                        accI[mf][nf] = __builtin_amdgcn_mfma_f32_16x16x32_bf16(
                            a[mf], bIv[nf], accI[mf][nf], 0, 0, 0);
                        accU[mf][nf] = __builtin_amdgcn_mfma_f32_16x16x32_bf16(
                            a[mf], bUv[nf], accU[mf][nf], 0, 0, 0);
                    }
            }
            __syncthreads();
        }

        // epilogue: gates -> LDS tiles [128][64] u16, then coalesced u32 copy-out
        u16* __restrict__ Lh = (u16*)Ash;
        u16* __restrict__ Lc = (u16*)Bsh;
        #pragma unroll
        for (int nf = 0; nf < 2; ++nf) {
            const int cl = wc * 32 + nf * 16 + m16;
            const int ch = chbase + cl;
            const float bi = bI[ch];           // recurrent biases apply at leaves
            const float bu = bU[ch];
            #pragma unroll
            for (int mf = 0; mf < 4; ++mf) {
                #pragma unroll
                for (int r4 = 0; r4 < 4; ++r4) {
                    const float cn = sigm(accI[mf][nf][r4] + bi) * ftanh(accU[mf][nf][r4] + bu);
                    const int nl = wr * 64 + mf * 16 + q * 4 + r4;
                    Lc[nl * 64 + cl] = f2bf(cn);
                    Lh[nl * 64 + cl] = f2bf(ftanh(cn));
                }
            }
        }
        __syncthreads();
        const u32* __restrict__ Lh2 = (const u32*)Lh;
        const u32* __restrict__ Lc2 = (const u32*)Lc;
        u32* __restrict__ hb2g = (u32*)hb;
        u32* __restrict__ cb2g = (u32*)cb;
        for (int e = tid; e < 4096; e += 256) {          // 128 rows x 32 u32
            const int row = e >> 5, ci = e & 31;
            const size_t dst = (size_t)(row0 + row) * 128 + (chbase >> 1) + ci;
            hb2g[dst] = Lh2[e];
            cb2g[dst] = Lc2[e];
        }
    } else {
        // ---- proj: [16384 x 320] x [320 x 768] -> pre ----
        const int B2 = blockIdx.x - 1536;
        const int xcd = B2 & 7, tt = B2 >> 3;
        const int c = tt % 6, rg = tt / 6;
        const int row0 = (rg * 8 + xcd) * 128;
        const int n0   = c * 128;

        auto stage = [&](int kt, int buf) {
            const int base = buf << 10;
            #pragma unroll
            for (int i = 0; i < 4; ++i) {
                const int sI = w * 256 + i * 64 + lane;
                const int r = sI >> 3, gs = sI & 7;
                const int g = gs ^ (r & 7);
                gll16(Xv + (size_t)(row0 + r) * 40 + kt * 8 + g, &Ash[base + sI]);
            }
            #pragma unroll
            for (int i = 0; i < 4; ++i) {
                const int sI = w * 256 + i * 64 + lane;
                const int br = sI >> 3, gs = sI & 7;
                const int g = gs ^ (br & 7);
                gll16(Wv + (size_t)(n0 + br) * 40 + kt * 8 + g, &Bsh[base + sI]);
            }
        };

        f32x4 acc[4][4];
        #pragma unroll
        for (int mf = 0; mf < 4; ++mf)
            #pragma unroll
            for (int nf = 0; nf < 4; ++nf) acc[mf][nf] = (f32x4)0.f;

        stage(0, 0);
        __syncthreads();
        for (int kt = 0; kt < 5; ++kt) {
            const int cur = kt & 1;
            if (kt < 4) stage(kt + 1, cur ^ 1);
            const int base = cur << 10;
            #pragma unroll
            for (int ks = 0; ks < 2; ++ks) {
                const int kg = ks * 4 + q;
                bf16x8 a[4], b[4];
                #pragma unroll
                for (int mf = 0; mf < 4; ++mf)
                    a[mf] = Ash[base + lidx(wr * 64 + mf * 16 + m16, kg)];
                #pragma unroll
                for (int nf = 0; nf < 4; ++nf)
                    b[nf] = Bsh[base + lidx(wc * 64 + nf * 16 + m16, kg)];
                #pragma unroll
                for (int mf = 0; mf < 4; ++mf)
                    #pragma unroll
                    for (int nf = 0; nf < 4; ++nf)
                        acc[mf][nf] = __builtin_amdgcn_mfma_f32_16x16x32_bf16(
                            a[mf], b[nf], acc[mf][nf], 0, 0, 0);
            }
            __syncthreads();
        }

        // epilogue: LDS tile [128][128] u16 across Ash+Bsh? fits in Ash alone (32KB)
        u16* __restrict__ Lp = (u16*)Ash;
        #pragma unroll
        for (int mf = 0; mf < 4; ++mf)
            #pragma unroll
            for (int nf = 0; nf < 4; ++nf) {
                const int cl = wc * 64 + nf * 16 + m16;
                #pragma unroll
                for (int r4 = 0; r4 < 4; ++r4) {
                    const int nl = wr * 64 + mf * 16 + q * 4 + r4;
                    Lp[nl * 128 + cl] = f2bf(acc[mf][nf][r4]);
                }
            }
        __syncthreads();
        const u32* __restrict__ Lp2 = (const u32*)Lp;
        u32* __restrict__ pre2g = (u32*)pre;
        for (int e = tid; e < 8192; e += 256) {          // 128 rows x 64 u32
            const int row = e >> 6, ci = e & 63;
            pre2g[(size_t)(row0 + row) * 384 + (n0 >> 1) + ci] = Lp2[e];
        }
    }
}

// ---- per-level recurrent GEMM; F epilogue computes fc; level-0 IU reg-hsum ----
__global__ __launch_bounds__(256) void rec_gemm(
    const u16* __restrict__ hb, const u16* __restrict__ hsb,
    const u16* __restrict__ Whb, const u16* __restrict__ pre,
    const float* __restrict__ bF, const u16* __restrict__ cb,
    u16* __restrict__ projIU, float* __restrict__ fcbuf,
    int s, int crow0, int L, int bigIU)
{
    __shared__ bf16x8 Ash[2048];
    __shared__ bf16x8 Bsh[2048];

    const int nIUrb = (L + 127) >> 7;
    const int bid   = blockIdx.x;

    bool isIU; int rb, cbk;
    if (bid < nIUrb * 4) { isIU = true;  rb = bid >> 2; cbk = bid & 3; }
    else { isIU = false; const int b2 = bid - nIUrb * 4; rb = b2 >> 1; cbk = b2 & 1; }

    const int row0  = rb * 128;
    const int Brow0 = isIU ? cbk * 128 : 512 + cbk * 128;
    const int ocol0 = cbk * 128;

    const int tid  = threadIdx.x;
    const int lane = tid & 63;
    const int w    = tid >> 6;
    const int wr   = w >> 1, wc = w & 1;
    const int m16  = lane & 15, q = lane >> 4;

    const bf16x8* __restrict__ Hv = (const bf16x8*)hb;
    const bf16x8* __restrict__ Sv = (const bf16x8*)hsb;
    const bf16x8* __restrict__ Wv = (const bf16x8*)Whb;

    auto stage = [&](int kt, int buf) {
        const int base = buf << 10;
        if (isIU && bigIU) {
            #pragma unroll
            for (int i = 0; i < 4; ++i) {
                const int G = tid + i * 256;
                const int r = G >> 3, g = G & 7;
                bf16x8 val;
                if (row0 + r < L) {
                    const size_t cg0 = (size_t)(crow0 + 4 * (row0 + r)) * 32 + kt * 8 + g;
                    BF8 x0, x1, x2, x3, o;
                    x0.v = Hv[cg0]; x1.v = Hv[cg0 + 32];
                    x2.v = Hv[cg0 + 64]; x3.v = Hv[cg0 + 96];
                    #pragma unroll
                    for (int j = 0; j < 8; ++j)
                        o.u[j] = f2bf(bf2f(x0.u[j]) + bf2f(x1.u[j])
                                    + bf2f(x2.u[j]) + bf2f(x3.u[j]));
                    val = o.v;
                } else {
                    BF8 z;
                    #pragma unroll
                    for (int j = 0; j < 8; ++j) z.u[j] = 0;
                    val = z.v;
                }
                Ash[base + lidx(r, g)] = val;
            }
        } else {
            #pragma unroll
            for (int i = 0; i < 4; ++i) {
                const int sI = w * 256 + i * 64 + lane;
                const int r = sI >> 3, gs = sI & 7;
                const int g = gs ^ (r & 7);
                if (isIU) {
                    gll16(Sv + (size_t)(s + row0 + r) * 32 + kt * 8 + g, &Ash[base + sI]);
                } else {
                    int arow = crow0 + row0 + r;
                    if (arow > NTOT) arow = NTOT;
                    gll16(Hv + (size_t)arow * 32 + kt * 8 + g, &Ash[base + sI]);
                }
            }
        }
        #pragma unroll
        for (int i = 0; i < 4; ++i) {
            const int sI = w * 256 + i * 64 + lane;
            const int br = sI >> 3, gs = sI & 7;
            const int g = gs ^ (br & 7);
            gll16(Wv + (size_t)(Brow0 + br) * 32 + kt * 8 + g, &Bsh[base + sI]);
        }
    };

    f32x4 acc[4][4];
    #pragma unroll
    for (int mf = 0; mf < 4; ++mf)
        #pragma unroll
        for (int nf = 0; nf < 4; ++nf) acc[mf][nf] = (f32x4)0.f;

    stage(0, 0);
    __syncthreads();
    for (int kt = 0; kt < 4; ++kt) {
        const int cur = kt & 1;
        if (kt < 3) stage(kt + 1, cur ^ 1);
        const int base = cur << 10;
        #pragma unroll
        for (int ks = 0; ks < 2; ++ks) {
            const int kg = ks * 4 + q;
            bf16x8 a[4], b[4];
            #pragma unroll
            for (int mf = 0; mf < 4; ++mf)
                a[mf] = Ash[base + lidx(wr * 64 + mf * 16 + m16, kg)];
            #pragma unroll
            for (int nf = 0; nf < 4; ++nf)
                b[nf] = Bsh[base + lidx(wc * 64 + nf * 16 + m16, kg)];
            #pragma unroll
            for (int mf = 0; mf < 4; ++mf)
                #pragma unroll
                for (int nf = 0; nf < 4; ++nf)
                    acc[mf][nf] = __builtin_amdgcn_mfma_f32_16x16x32_bf16(
                        a[mf], b[nf], acc[mf][nf], 0, 0, 0);
        }
        __syncthreads();
    }

    if (isIU) {
        #pragma unroll
        for (int mf = 0; mf < 4; ++mf)
            #pragma unroll
            for (int nf = 0; nf < 4; ++nf) {
                const int col = ocol0 + wc * 64 + nf * 16 + m16;
                #pragma unroll
                for (int r4 = 0; r4 < 4; ++r4) {
                    const int orow = row0 + wr * 64 + mf * 16 + q * 4 + r4;
                    projIU[(size_t)orow * 512 + col] = f2bf(acc[mf][nf][r4]);
                }
            }
    } else {
        #pragma unroll
        for (int mf = 0; mf < 4; ++mf) {
            const int off  = wr * 64 + mf * 16 + q * 4;
            const int goff = (row0 + off) >> 2;
            if (goff < L) {
                #pragma unroll
                for (int nf = 0; nf < 4; ++nf) {
                    const int col = ocol0 + wc * 64 + nf * 16 + m16;
                    const float fpre = bf2f(pre[(size_t)(s + goff) * 768 + 512 + col]) + bF[col];
                    float fc = 0.f;
                    #pragma unroll
                    for (int r4 = 0; r4 < 4; ++r4) {
                        int child = crow0 + row0 + off + r4;
                        if (child > NTOT) child = NTOT;
                        const float cc = bf2f(cb[(size_t)child * HH + col]);
                        fc = fmaf(sigm(acc[mf][nf][r4] + fpre), cc, fc);
                    }
                    fcbuf[(size_t)goff * HH + col] = fc;
                }
            }
        }
    }
}

// ---- per-level gates (+ hsum_small partition on level 0) ----
__global__ __launch_bounds__(256) void gate_kernel(
    const u32* __restrict__ pre2, const u32* __restrict__ pIU2,
    const float* __restrict__ fcbuf,
    const float* __restrict__ bI, const float* __restrict__ bU,
    u32* __restrict__ hb2, u32* __restrict__ cb2, u32* __restrict__ hsumb2,
    float* __restrict__ out, int s, int L)
{
    const int t  = threadIdx.x;
    const int j2 = t & 127;

    if (L == 1) {                                        // root node 0
        if (t >= 128) return;
        const float2 vbi = ((const float2*)bI)[j2];
        const float2 vbu = ((const float2*)bU)[j2];
        const u32 pi = pre2[j2];
        const u32 pu = pre2[128 + j2];
        const u32 ri = pIU2[j2];
        const u32 ru = pIU2[128 + j2];
        const float aI0 = bf2f((u16)pi) + bf2f((u16)ri) + vbi.x;
        const float aI1 = bf2f((u16)(pi >> 16)) + bf2f((u16)(ri >> 16)) + vbi.y;
        const float aU0 = bf2f((u16)pu) + bf2f((u16)ru) + vbu.x;
        const float aU1 = bf2f((u16)(pu >> 16)) + bf2f((u16)(ru >> 16)) + vbu.y;
        const float2 fc = ((const float2*)fcbuf)[j2];
        const float cn0 = fmaf(sigm(aI0), ftanh(aU0), fc.x);
        const float cn1 = fmaf(sigm(aI1), ftanh(aU1), fc.y);
        const float hn0 = ftanh(cn0);
        const float hn1 = ftanh(cn1);
        hb2[j2] = (u32)f2bf(hn0) | ((u32)f2bf(hn1) << 16);
        cb2[j2] = (u32)f2bf(cn0) | ((u32)f2bf(cn1) << 16);
        ((float2*)out)[j2] = make_float2(hn0, hn1);
        ((float2*)(out + 256))[j2] = make_float2(cn0, cn1);
        return;
    }

    const int ng = (L + 3) >> 2;
    const int gateBlocks = (ng + 1) >> 1;
    if ((int)blockIdx.x >= gateBlocks) {
        const int id = ((int)blockIdx.x - gateBlocks) * 256 + t;
        if (id < 1365 * 128) {
            const int ploc = id >> 7, jj = id & 127;
            const int p = 4096 + ploc;
            const int c0 = 4 * p + 1;
            float s0 = 0.f, s1 = 0.f;
            #pragma unroll
            for (int k = 0; k < 4; ++k) {
                const u32 v = hb2[(size_t)(c0 + k) * 128 + jj];
                s0 += bf2f((u16)v);
                s1 += bf2f((u16)(v >> 16));
            }
            hsumb2[(size_t)p * 128 + jj] = (u32)f2bf(s0) | ((u32)f2bf(s1) << 16);
        }
        return;
    }

    const float2 vbi = ((const float2*)bI)[j2];
    const float2 vbu = ((const float2*)bU)[j2];
    const int g = blockIdx.x * 2 + (t >> 7);
    if (g >= ng) return;
    const int p = ((s - 1) >> 2) + g;

    float hs0 = 0.f, hs1 = 0.f;
    #pragma unroll
    for (int k = 0; k < 4; ++k) {
        const int nloc = 4 * g + k;
        const int n = s + nloc;
        if (nloc < L) {
            const u32 pi = pre2[(size_t)n * 384 + j2];
            const u32 pu = pre2[(size_t)n * 384 + 128 + j2];
            const u32 ri = pIU2[(size_t)nloc * 256 + j2];
            const u32 ru = pIU2[(size_t)nloc * 256 + 128 + j2];
            const float aI0 = bf2f((u16)pi) + bf2f((u16)ri) + vbi.x;
            const float aI1 = bf2f((u16)(pi >> 16)) + bf2f((u16)(ri >> 16)) + vbi.y;
            const float aU0 = bf2f((u16)pu) + bf2f((u16)ru) + vbu.x;
            const float aU1 = bf2f((u16)(pu >> 16)) + bf2f((u16)(ru >> 16)) + vbu.y;
            const float2 fc = ((const float2*)fcbuf)[(size_t)nloc * 128 + j2];
            const float cn0 = fmaf(sigm(aI0), ftanh(aU0), fc.x);
            const float cn1 = fmaf(sigm(aI1), ftanh(aU1), fc.y);
            const float hn0 = ftanh(cn0);
            const float hn1 = ftanh(cn1);
            hb2[(size_t)n * 128 + j2] = (u32)f2bf(hn0) | ((u32)f2bf(hn1) << 16);
            cb2[(size_t)n * 128 + j2] = (u32)f2bf(cn0) | ((u32)f2bf(cn1) << 16);
            hs0 += hn0; hs1 += hn1;
        } else {
            const u32 v = hb2[(size_t)n * 128 + j2];
            hs0 += bf2f((u16)v);
            hs1 += bf2f((u16)(v >> 16));
        }
    }
    hsumb2[(size_t)p * 128 + j2] = (u32)f2bf(hs0) | ((u32)f2bf(hs1) << 16);
}

extern "C" void kernel_launch(void* const* d_in, const int* in_sizes, int n_in,
                              void* d_out, int out_size, void* d_ws, size_t ws_size,
                              hipStream_t stream) {
    const float* X   = (const float*)d_in[0];
    const float* ixw = (const float*)d_in[1];
    const float* ixb = (const float*)d_in[2];
    const float* ihw = (const float*)d_in[3];
    const float* ihb = (const float*)d_in[4];
    const float* uxw = (const float*)d_in[5];
    const float* uxb = (const float*)d_in[6];
    const float* uhw = (const float*)d_in[7];
    const float* uhb = (const float*)d_in[8];
    const float* fiw = (const float*)d_in[9];
    const float* fib = (const float*)d_in[10];
    const float* fhw = (const float*)d_in[11];
    const float* fhb = (const float*)d_in[12];
    float* out = (float*)d_out;

    char* ws = (char*)d_ws;
    u16* hb   = (u16*)(ws + OFF_HB);
    u16* cb   = (u16*)(ws + OFF_CB);
    u16* pre  = (u16*)(ws + OFF_PRE);
    u16* Wxb  = (u16*)(ws + OFF_WXB);
    u16* Whb  = (u16*)(ws + OFF_WHB);
    u16* Xb   = (u16*)(ws + OFF_XB);
    u16* pIU  = (u16*)(ws + OFF_PIU);
    float* fc = (float*)(ws + OFF_FC);
    u16* hsb  = (u16*)(ws + OFF_HSB);
    float* bI = (float*)(ws + OFF_BI);
    float* bU = (float*)(ws + OFF_BU);
    float* bF = (float*)(ws + OFF_BF);

    conv_all<<<2912, 256, 0, stream>>>(X, ixw, uxw, fiw, ihw, uhw, fhw,
        ixb, ihb, uxb, uhb, fib, fhb,
        (u32*)Xb, (u32*)Wxb, (u32*)Whb, hb, cb, bI, bU, bF);

    lp_gemm<<<2304, 256, 0, stream>>>(Xb, Wxb, bI, bU, hb, cb, pre);

    const int starts[8] = {5461, 1365, 341, 85, 21, 5, 1, 0};
    const int ends[8]   = {16384, 5461, 1365, 341, 85, 21, 5, 1};
    for (int l = 0; l < 8; ++l) {
        const int s = starts[l], e = ends[l];
        const int L = e - s;
        const int crow0 = 4 * s + 1;
        const int nIUrb = (L + 127) >> 7;
        const int nFrb  = (4 * L + 127) >> 7;
        rec_gemm<<<nIUrb * 4 + nFrb * 2, 256, 0, stream>>>(hb, hsb, Whb, pre, bF, cb,
            pIU, fc, s, crow0, L, (l == 0) ? 1 : 0);
        const int ng = (L + 3) >> 2;
        const int gateBlocks = (ng + 1) >> 1;
        const int hsBlocks = (l == 0) ? 683 : 0;
        gate_kernel<<<gateBlocks + hsBlocks, 256, 0, stream>>>(
            (const u32*)pre, (const u32*)pIU, fc, bI, bU,
            (u32*)hb, (u32*)cb, (u32*)hsb, out, s, L);
    }
}

// Round 18
// 185.441 us; speedup vs baseline: 1.5605x; 1.0233x over previous
//
#include <hip/hip_runtime.h>
#include <hip/hip_bf16.h>

// ChildSum TreeLSTM, complete 4-ary tree. N=65536, D=300(->320), H=256, K=4.
// Internal [0,16384), leaves [16384,65536). Children of n: 4n+1..4n+4.
// Round 18: R15 structure exactly (best 186.6us; R17's LDS-staged epilogue
// reverted — it added bank conflicts and cost 3us). New: conv_all uses
// float4 loads + uint2 packed stores (rows are 16B-aligned, DD%4==0).

#define NTOT 65536
#define DD   300
#define KP   320
#define HH   256
#define LEAF_START 16384
#define LOG2E 1.4426950408889634f

typedef unsigned short u16;
typedef unsigned int   u32;
typedef __attribute__((ext_vector_type(8))) short bf16x8;
typedef __attribute__((ext_vector_type(4))) float f32x4;

union BF8 { bf16x8 v; u16 u[8]; };

// ---- ws layout (bytes) ----
#define OFF_HB    0ull                                   // [65537][256] bf16
#define OFF_CB    33554944ull                            // [65537][256] bf16
#define OFF_PRE   67109888ull                            // [16384][768] bf16
#define OFF_WXB   92275712ull                            // [768][320] bf16
#define OFF_WHB   92767232ull                            // [768][256] bf16
#define OFF_XB    93160448ull                            // [65536][320] bf16
#define OFF_PIU   135103488ull                           // [11008][512] bf16
#define OFF_FC    146375680ull                           // [11008][256] f32
#define OFF_HSB   157647872ull                           // [16512][256] bf16
#define OFF_BI    166102016ull                           // [256] f32
#define OFF_BU    166103040ull
#define OFF_BF    166104064ull

__device__ __forceinline__ float frcp(float x) { return __builtin_amdgcn_rcpf(x); }
__device__ __forceinline__ float fex2(float x) { return __builtin_amdgcn_exp2f(x); }
__device__ __forceinline__ float sigm(float x)  { return frcp(1.f + fex2(-LOG2E * x)); }
__device__ __forceinline__ float ftanh(float x) { return 1.f - 2.f * frcp(1.f + fex2(2.f * LOG2E * x)); }

__device__ __forceinline__ u16 f2bf(float f) {
    __hip_bfloat16 b = __float2bfloat16(f);
    u16 u; __builtin_memcpy(&u, &b, 2); return u;
}
__device__ __forceinline__ float bf2f(u16 b) {
    union { u32 u; float f; } v; v.u = ((u32)b) << 16;
    return v.f;
}
__device__ __forceinline__ int lidx(int r, int g) { return (r << 3) | (g ^ (r & 7)); }

__device__ __forceinline__ void gll16(const void* g, void* l) {
    __builtin_amdgcn_global_load_lds(
        (const __attribute__((address_space(1))) unsigned int*)g,
        (__attribute__((address_space(3))) unsigned int*)l, 16, 0, 0);
}

__device__ __forceinline__ uint2 pack4(float4 f) {
    uint2 r;
    r.x = (u32)f2bf(f.x) | ((u32)f2bf(f.y) << 16);
    r.y = (u32)f2bf(f.z) | ((u32)f2bf(f.w) << 16);
    return r;
}

// ---- merged conversions (vectorized): conv_x | conv_wx | conv_wh(+init) ----
__global__ __launch_bounds__(256) void conv_all(
    const float* __restrict__ X,
    const float* __restrict__ ixw, const float* __restrict__ uxw,
    const float* __restrict__ fiw,
    const float* __restrict__ ihw, const float* __restrict__ uhw,
    const float* __restrict__ fhw,
    const float* __restrict__ ixb, const float* __restrict__ ihb,
    const float* __restrict__ uxb, const float* __restrict__ uhb,
    const float* __restrict__ fib, const float* __restrict__ fhb,
    u32* __restrict__ Xb2, u32* __restrict__ Wxb2, u32* __restrict__ Whb2,
    u16* __restrict__ hb, u16* __restrict__ cb,
    float* __restrict__ bI, float* __restrict__ bU, float* __restrict__ bF)
{
    const int b = blockIdx.x;
    const int t = threadIdx.x;
    if (b < 2048) {                                      // X -> Xb (quads of 4 f32)
        const size_t total = (size_t)NTOT * 80;          // 80 quads per 320-row
        uint2* __restrict__ dst = (uint2*)Xb2;
        for (size_t id = (size_t)b * 256 + t; id < total; id += (size_t)2048 * 256) {
            const int node = (int)(id / 80);
            const int p    = (int)(id % 80);
            float4 f = make_float4(0.f, 0.f, 0.f, 0.f);
            if (p < 75) f = *(const float4*)(X + (size_t)node * DD + p * 4);
            dst[id] = pack4(f);
        }
    } else if (b < 2528) {                               // [ixw;uxw;fiw] -> Wxb
        const int b2 = b - 2048;
        const int total = 768 * 80;
        uint2* __restrict__ dst = (uint2*)Wxb2;
        for (int id = b2 * 256 + t; id < total; id += 480 * 256) {
            const int row = id / 80;
            const int p   = id % 80;
            const float* src = (row < 256) ? (ixw + (size_t)row * DD)
                             : (row < 512) ? (uxw + (size_t)(row - 256) * DD)
                                           : (fiw + (size_t)(row - 512) * DD);
            float4 f = make_float4(0.f, 0.f, 0.f, 0.f);
            if (p < 75) f = *(const float4*)(src + p * 4);
            dst[id] = pack4(f);
        }
    } else {                                             // [ihw;uhw;fhw] -> Whb
        const int b3 = b - 2528;
        if (b3 == 0) {
            hb[(size_t)NTOT * HH + t] = 0;
            cb[(size_t)NTOT * HH + t] = 0;
            bI[t] = ixb[t] + ihb[t];
            bU[t] = uxb[t] + uhb[t];
            bF[t] = fib[t] + fhb[t];
        }
        const int total = 768 * 64;                      // 64 quads per 256-row
        uint2* __restrict__ dst = (uint2*)Whb2;
        for (int id = b3 * 256 + t; id < total; id += 384 * 256) {
            const int row = id / 64;
            const int p   = id % 64;
            const float* src = (row < 256) ? (ihw + (size_t)row * HH)
                             : (row < 512) ? (uhw + (size_t)(row - 256) * HH)
                                           : (fhw + (size_t)(row - 512) * HH);
            const float4 f = *(const float4*)(src + p * 4);
            dst[id] = pack4(f);
        }
    }
}

// ---- merged leaf + proj GEMM, 2-phase gll16 staging, XCD-swizzled blocks ----
__global__ __launch_bounds__(256) void lp_gemm(
    const u16* __restrict__ Xb, const u16* __restrict__ Wxb,
    const float* __restrict__ bI, const float* __restrict__ bU,
    u16* __restrict__ hb, u16* __restrict__ cb, u16* __restrict__ pre)
{
    __shared__ bf16x8 Ash[2048];
    __shared__ bf16x8 Bsh[2048];

    const int tid  = threadIdx.x;
    const int lane = tid & 63;
    const int w    = tid >> 6;
    const int wr   = w >> 1, wc = w & 1;
    const int m16  = lane & 15, q = lane >> 4;

    const bf16x8* __restrict__ Xv = (const bf16x8*)Xb;   // 40 granules/row
    const bf16x8* __restrict__ Wv = (const bf16x8*)Wxb;

    if (blockIdx.x < 1536) {
        // ---- leaf: 128 nodes x 64 ch, B-tile = [64 ix | 64 ux] ----
        const int xcd = blockIdx.x & 7, tt = blockIdx.x >> 3;
        const int c = tt & 3, rg = tt >> 2;
        const int row0   = LEAF_START + (rg * 8 + xcd) * 128;
        const int chbase = c * 64;

        auto stage = [&](int kt, int buf) {
            const int base = buf << 10;
            #pragma unroll
            for (int i = 0; i < 4; ++i) {
                const int sI = w * 256 + i * 64 + lane;
                const int r = sI >> 3, gs = sI & 7;
                const int g = gs ^ (r & 7);
                gll16(Xv + (size_t)(row0 + r) * 40 + kt * 8 + g, &Ash[base + sI]);
            }
            #pragma unroll
            for (int i = 0; i < 4; ++i) {
                const int sI = w * 256 + i * 64 + lane;
                const int br = sI >> 3, gs = sI & 7;
                const int g = gs ^ (br & 7);
                const int srow = ((br >> 6) << 8) + chbase + (br & 63);
                gll16(Wv + (size_t)srow * 40 + kt * 8 + g, &Bsh[base + sI]);
            }
        };

        f32x4 accI[4][2], accU[4][2];
        #pragma unroll
        for (int mf = 0; mf < 4; ++mf)
            #pragma unroll
            for (int nf = 0; nf < 2; ++nf) { accI[mf][nf] = (f32x4)0.f; accU[mf][nf] = (f32x4)0.f; }

        stage(0, 0);
        __syncthreads();
        for (int kt = 0; kt < 5; ++kt) {
            const int cur = kt & 1;
            if (kt < 4) stage(kt + 1, cur ^ 1);
            const int base = cur << 10;
            #pragma unroll
            for (int ks = 0; ks < 2; ++ks) {
                const int kg = ks * 4 + q;
                bf16x8 a[4], bIv[2], bUv[2];
                #pragma unroll
                for (int mf = 0; mf < 4; ++mf)
                    a[mf] = Ash[base + lidx(wr * 64 + mf * 16 + m16, kg)];
                #pragma unroll
                for (int nf = 0; nf < 2; ++nf) {
                    bIv[nf] = Bsh[base + lidx(wc * 32 + nf * 16 + m16, kg)];
                    bUv[nf] = Bsh[base + lidx(64 + wc * 32 + nf * 16 + m16, kg)];
                }
                #pragma unroll
                for (int mf = 0; mf < 4; ++mf)
                    #pragma unroll
                    for (int nf = 0; nf < 2; ++nf) {
                        accI[mf][nf] = __builtin_amdgcn_mfma_f32_16x16x32_bf16(
                            a[mf], bIv[nf], accI[mf][nf], 0, 0, 0);
                        accU[mf][nf] = __builtin_amdgcn_mfma_f32_16x16x32_bf16(
                            a[mf], bUv[nf], accU[mf][nf], 0, 0, 0);
                    }
            }
            __syncthreads();
        }

        #pragma unroll
        for (int nf = 0; nf < 2; ++nf) {
            const int ch = chbase + wc * 32 + nf * 16 + m16;
            const float bi = bI[ch];           // recurrent biases apply at leaves
            const float bu = bU[ch];
            #pragma unroll
            for (int mf = 0; mf < 4; ++mf) {
                #pragma unroll
                for (int r4 = 0; r4 < 4; ++r4) {
                    const float cn = sigm(accI[mf][nf][r4] + bi) * ftanh(accU[mf][nf][r4] + bu);
                    const int node = row0 + wr * 64 + mf * 16 + q * 4 + r4;
                    const size_t off = (size_t)node * HH + ch;
                    cb[off] = f2bf(cn);
                    hb[off] = f2bf(ftanh(cn));
                }
            }
        }
    } else {
        // ---- proj: [16384 x 320] x [320 x 768] -> pre ----
        const int B2 = blockIdx.x - 1536;
        const int xcd = B2 & 7, tt = B2 >> 3;
        const int c = tt % 6, rg = tt / 6;
        const int row0 = (rg * 8 + xcd) * 128;
        const int n0   = c * 128;

        auto stage = [&](int kt, int buf) {
            const int base = buf << 10;
            #pragma unroll
            for (int i = 0; i < 4; ++i) {
                const int sI = w * 256 + i * 64 + lane;
                const int r = sI >> 3, gs = sI & 7;
                const int g = gs ^ (r & 7);
                gll16(Xv + (size_t)(row0 + r) * 40 + kt * 8 + g, &Ash[base + sI]);
            }
            #pragma unroll
            for (int i = 0; i < 4; ++i) {
                const int sI = w * 256 + i * 64 + lane;
                const int br = sI >> 3, gs = sI & 7;
                const int g = gs ^ (br & 7);
                gll16(Wv + (size_t)(n0 + br) * 40 + kt * 8 + g, &Bsh[base + sI]);
            }
        };

        f32x4 acc[4][4];
        #pragma unroll
        for (int mf = 0; mf < 4; ++mf)
            #pragma unroll
            for (int nf = 0; nf < 4; ++nf) acc[mf][nf] = (f32x4)0.f;

        stage(0, 0);
        __syncthreads();
        for (int kt = 0; kt < 5; ++kt) {
            const int cur = kt & 1;
            if (kt < 4) stage(kt + 1, cur ^ 1);
            const int base = cur << 10;
            #pragma unroll
            for (int ks = 0; ks < 2; ++ks) {
                const int kg = ks * 4 + q;
                bf16x8 a[4], b[4];
                #pragma unroll
                for (int mf = 0; mf < 4; ++mf)
                    a[mf] = Ash[base + lidx(wr * 64 + mf * 16 + m16, kg)];
                #pragma unroll
                for (int nf = 0; nf < 4; ++nf)
                    b[nf] = Bsh[base + lidx(wc * 64 + nf * 16 + m16, kg)];
                #pragma unroll
                for (int mf = 0; mf < 4; ++mf)
                    #pragma unroll
                    for (int nf = 0; nf < 4; ++nf)
                        acc[mf][nf] = __builtin_amdgcn_mfma_f32_16x16x32_bf16(
                            a[mf], b[nf], acc[mf][nf], 0, 0, 0);
            }
            __syncthreads();
        }

        #pragma unroll
        for (int mf = 0; mf < 4; ++mf)
            #pragma unroll
            for (int nf = 0; nf < 4; ++nf) {
                const int col = n0 + wc * 64 + nf * 16 + m16;
                #pragma unroll
                for (int r4 = 0; r4 < 4; ++r4) {
                    const int node = row0 + wr * 64 + mf * 16 + q * 4 + r4;
                    pre[(size_t)node * 768 + col] = f2bf(acc[mf][nf][r4]);
                }
            }
    }
}

// ---- per-level recurrent GEMM; F epilogue computes fc; level-0 IU reg-hsum ----
__global__ __launch_bounds__(256) void rec_gemm(
    const u16* __restrict__ hb, const u16* __restrict__ hsb,
    const u16* __restrict__ Whb, const u16* __restrict__ pre,
    const float* __restrict__ bF, const u16* __restrict__ cb,
    u16* __restrict__ projIU, float* __restrict__ fcbuf,
    int s, int crow0, int L, int bigIU)
{
    __shared__ bf16x8 Ash[2048];
    __shared__ bf16x8 Bsh[2048];

    const int nIUrb = (L + 127) >> 7;
    const int bid   = blockIdx.x;

    bool isIU; int rb, cbk;
    if (bid < nIUrb * 4) { isIU = true;  rb = bid >> 2; cbk = bid & 3; }
    else { isIU = false; const int b2 = bid - nIUrb * 4; rb = b2 >> 1; cbk = b2 & 1; }

    const int row0  = rb * 128;
    const int Brow0 = isIU ? cbk * 128 : 512 + cbk * 128;
    const int ocol0 = cbk * 128;

    const int tid  = threadIdx.x;
    const int lane = tid & 63;
    const int w    = tid >> 6;
    const int wr   = w >> 1, wc = w & 1;
    const int m16  = lane & 15, q = lane >> 4;

    const bf16x8* __restrict__ Hv = (const bf16x8*)hb;
    const bf16x8* __restrict__ Sv = (const bf16x8*)hsb;
    const bf16x8* __restrict__ Wv = (const bf16x8*)Whb;

    auto stage = [&](int kt, int buf) {
        const int base = buf << 10;
        if (isIU && bigIU) {
            #pragma unroll
            for (int i = 0; i < 4; ++i) {
                const int G = tid + i * 256;
                const int r = G >> 3, g = G & 7;
                bf16x8 val;
                if (row0 + r < L) {
                    const size_t cg0 = (size_t)(crow0 + 4 * (row0 + r)) * 32 + kt * 8 + g;
                    BF8 x0, x1, x2, x3, o;
                    x0.v = Hv[cg0]; x1.v = Hv[cg0 + 32];
                    x2.v = Hv[cg0 + 64]; x3.v = Hv[cg0 + 96];
                    #pragma unroll
                    for (int j = 0; j < 8; ++j)
                        o.u[j] = f2bf(bf2f(x0.u[j]) + bf2f(x1.u[j])
                                    + bf2f(x2.u[j]) + bf2f(x3.u[j]));
                    val = o.v;
                } else {
                    BF8 z;
                    #pragma unroll
                    for (int j = 0; j < 8; ++j) z.u[j] = 0;
                    val = z.v;
                }
                Ash[base + lidx(r, g)] = val;
            }
        } else {
            #pragma unroll
            for (int i = 0; i < 4; ++i) {
                const int sI = w * 256 + i * 64 + lane;
                const int r = sI >> 3, gs = sI & 7;
                const int g = gs ^ (r & 7);
                if (isIU) {
                    gll16(Sv + (size_t)(s + row0 + r) * 32 + kt * 8 + g, &Ash[base + sI]);
                } else {
                    int arow = crow0 + row0 + r;
                    if (arow > NTOT) arow = NTOT;
                    gll16(Hv + (size_t)arow * 32 + kt * 8 + g, &Ash[base + sI]);
                }
            }
        }
        #pragma unroll
        for (int i = 0; i < 4; ++i) {
            const int sI = w * 256 + i * 64 + lane;
            const int br = sI >> 3, gs = sI & 7;
            const int g = gs ^ (br & 7);
            gll16(Wv + (size_t)(Brow0 + br) * 32 + kt * 8 + g, &Bsh[base + sI]);
        }
    };

    f32x4 acc[4][4];
    #pragma unroll
    for (int mf = 0; mf < 4; ++mf)
        #pragma unroll
        for (int nf = 0; nf < 4; ++nf) acc[mf][nf] = (f32x4)0.f;

    stage(0, 0);
    __syncthreads();
    for (int kt = 0; kt < 4; ++kt) {
        const int cur = kt & 1;
        if (kt < 3) stage(kt + 1, cur ^ 1);
        const int base = cur << 10;
        #pragma unroll
        for (int ks = 0; ks < 2; ++ks) {
            const int kg = ks * 4 + q;
            bf16x8 a[4], b[4];
            #pragma unroll
            for (int mf = 0; mf < 4; ++mf)
                a[mf] = Ash[base + lidx(wr * 64 + mf * 16 + m16, kg)];
            #pragma unroll
            for (int nf = 0; nf < 4; ++nf)
                b[nf] = Bsh[base + lidx(wc * 64 + nf * 16 + m16, kg)];
            #pragma unroll
            for (int mf = 0; mf < 4; ++mf)
                #pragma unroll
                for (int nf = 0; nf < 4; ++nf)
                    acc[mf][nf] = __builtin_amdgcn_mfma_f32_16x16x32_bf16(
                        a[mf], b[nf], acc[mf][nf], 0, 0, 0);
        }
        __syncthreads();
    }

    if (isIU) {
        #pragma unroll
        for (int mf = 0; mf < 4; ++mf)
            #pragma unroll
            for (int nf = 0; nf < 4; ++nf) {
                const int col = ocol0 + wc * 64 + nf * 16 + m16;
                #pragma unroll
                for (int r4 = 0; r4 < 4; ++r4) {
                    const int orow = row0 + wr * 64 + mf * 16 + q * 4 + r4;
                    projIU[(size_t)orow * 512 + col] = f2bf(acc[mf][nf][r4]);
                }
            }
    } else {
        #pragma unroll
        for (int mf = 0; mf < 4; ++mf) {
            const int off  = wr * 64 + mf * 16 + q * 4;
            const int goff = (row0 + off) >> 2;
            if (goff < L) {
                #pragma unroll
                for (int nf = 0; nf < 4; ++nf) {
                    const int col = ocol0 + wc * 64 + nf * 16 + m16;
                    const float fpre = bf2f(pre[(size_t)(s + goff) * 768 + 512 + col]) + bF[col];
                    float fc = 0.f;
                    #pragma unroll
                    for (int r4 = 0; r4 < 4; ++r4) {
                        int child = crow0 + row0 + off + r4;
                        if (child > NTOT) child = NTOT;
                        const float cc = bf2f(cb[(size_t)child * HH + col]);
                        fc = fmaf(sigm(acc[mf][nf][r4] + fpre), cc, fc);
                    }
                    fcbuf[(size_t)goff * HH + col] = fc;
                }
            }
        }
    }
}

// ---- per-level gates (+ hsum_small partition on level 0) ----
__global__ __launch_bounds__(256) void gate_kernel(
    const u32* __restrict__ pre2, const u32* __restrict__ pIU2,
    const float* __restrict__ fcbuf,
    const float* __restrict__ bI, const float* __restrict__ bU,
    u32* __restrict__ hb2, u32* __restrict__ cb2, u32* __restrict__ hsumb2,
    float* __restrict__ out, int s, int L)
{
    const int t  = threadIdx.x;
    const int j2 = t & 127;

    if (L == 1) {                                        // root node 0
        if (t >= 128) return;
        const float2 vbi = ((const float2*)bI)[j2];
        const float2 vbu = ((const float2*)bU)[j2];
        const u32 pi = pre2[j2];
        const u32 pu = pre2[128 + j2];
        const u32 ri = pIU2[j2];
        const u32 ru = pIU2[128 + j2];
        const float aI0 = bf2f((u16)pi) + bf2f((u16)ri) + vbi.x;
        const float aI1 = bf2f((u16)(pi >> 16)) + bf2f((u16)(ri >> 16)) + vbi.y;
        const float aU0 = bf2f((u16)pu) + bf2f((u16)ru) + vbu.x;
        const float aU1 = bf2f((u16)(pu >> 16)) + bf2f((u16)(ru >> 16)) + vbu.y;
        const float2 fc = ((const float2*)fcbuf)[j2];
        const float cn0 = fmaf(sigm(aI0), ftanh(aU0), fc.x);
        const float cn1 = fmaf(sigm(aI1), ftanh(aU1), fc.y);
        const float hn0 = ftanh(cn0);
        const float hn1 = ftanh(cn1);
        hb2[j2] = (u32)f2bf(hn0) | ((u32)f2bf(hn1) << 16);
        cb2[j2] = (u32)f2bf(cn0) | ((u32)f2bf(cn1) << 16);
        ((float2*)out)[j2] = make_float2(hn0, hn1);
        ((float2*)(out + 256))[j2] = make_float2(cn0, cn1);
        return;
    }

    const int ng = (L + 3) >> 2;
    const int gateBlocks = (ng + 1) >> 1;
    if ((int)blockIdx.x >= gateBlocks) {
        const int id = ((int)blockIdx.x - gateBlocks) * 256 + t;
        if (id < 1365 * 128) {
            const int ploc = id >> 7, jj = id & 127;
            const int p = 4096 + ploc;
            const int c0 = 4 * p + 1;
            float s0 = 0.f, s1 = 0.f;
            #pragma unroll
            for (int k = 0; k < 4; ++k) {
                const u32 v = hb2[(size_t)(c0 + k) * 128 + jj];
                s0 += bf2f((u16)v);
                s1 += bf2f((u16)(v >> 16));
            }
            hsumb2[(size_t)p * 128 + jj] = (u32)f2bf(s0) | ((u32)f2bf(s1) << 16);
        }
        return;
    }

    const float2 vbi = ((const float2*)bI)[j2];
    const float2 vbu = ((const float2*)bU)[j2];
    const int g = blockIdx.x * 2 + (t >> 7);
    if (g >= ng) return;
    const int p = ((s - 1) >> 2) + g;

    float hs0 = 0.f, hs1 = 0.f;
    #pragma unroll
    for (int k = 0; k < 4; ++k) {
        const int nloc = 4 * g + k;
        const int n = s + nloc;
        if (nloc < L) {
            const u32 pi = pre2[(size_t)n * 384 + j2];
            const u32 pu = pre2[(size_t)n * 384 + 128 + j2];
            const u32 ri = pIU2[(size_t)nloc * 256 + j2];
            const u32 ru = pIU2[(size_t)nloc * 256 + 128 + j2];
            const float aI0 = bf2f((u16)pi) + bf2f((u16)ri) + vbi.x;
            const float aI1 = bf2f((u16)(pi >> 16)) + bf2f((u16)(ri >> 16)) + vbi.y;
            const float aU0 = bf2f((u16)pu) + bf2f((u16)ru) + vbu.x;
            const float aU1 = bf2f((u16)(pu >> 16)) + bf2f((u16)(ru >> 16)) + vbu.y;
            const float2 fc = ((const float2*)fcbuf)[(size_t)nloc * 128 + j2];
            const float cn0 = fmaf(sigm(aI0), ftanh(aU0), fc.x);
            const float cn1 = fmaf(sigm(aI1), ftanh(aU1), fc.y);
            const float hn0 = ftanh(cn0);
            const float hn1 = ftanh(cn1);
            hb2[(size_t)n * 128 + j2] = (u32)f2bf(hn0) | ((u32)f2bf(hn1) << 16);
            cb2[(size_t)n * 128 + j2] = (u32)f2bf(cn0) | ((u32)f2bf(cn1) << 16);
            hs0 += hn0; hs1 += hn1;
        } else {
            const u32 v = hb2[(size_t)n * 128 + j2];
            hs0 += bf2f((u16)v);
            hs1 += bf2f((u16)(v >> 16));
        }
    }
    hsumb2[(size_t)p * 128 + j2] = (u32)f2bf(hs0) | ((u32)f2bf(hs1) << 16);
}

extern "C" void kernel_launch(void* const* d_in, const int* in_sizes, int n_in,
                              void* d_out, int out_size, void* d_ws, size_t ws_size,
                              hipStream_t stream) {
    const float* X   = (const float*)d_in[0];
    const float* ixw = (const float*)d_in[1];
    const float* ixb = (const float*)d_in[2];
    const float* ihw = (const float*)d_in[3];
    const float* ihb = (const float*)d_in[4];
    const float* uxw = (const float*)d_in[5];
    const float* uxb = (const float*)d_in[6];
    const float* uhw = (const float*)d_in[7];
    const float* uhb = (const float*)d_in[8];
    const float* fiw = (const float*)d_in[9];
    const float* fib = (const float*)d_in[10];
    const float* fhw = (const float*)d_in[11];
    const float* fhb = (const float*)d_in[12];
    float* out = (float*)d_out;

    char* ws = (char*)d_ws;
    u16* hb   = (u16*)(ws + OFF_HB);
    u16* cb   = (u16*)(ws + OFF_CB);
    u16* pre  = (u16*)(ws + OFF_PRE);
    u16* Wxb  = (u16*)(ws + OFF_WXB);
    u16* Whb  = (u16*)(ws + OFF_WHB);
    u16* Xb   = (u16*)(ws + OFF_XB);
    u16* pIU  = (u16*)(ws + OFF_PIU);
    float* fc = (float*)(ws + OFF_FC);
    u16* hsb  = (u16*)(ws + OFF_HSB);
    float* bI = (float*)(ws + OFF_BI);
    float* bU = (float*)(ws + OFF_BU);
    float* bF = (float*)(ws + OFF_BF);

    conv_all<<<2912, 256, 0, stream>>>(X, ixw, uxw, fiw, ihw, uhw, fhw,
        ixb, ihb, uxb, uhb, fib, fhb,
        (u32*)Xb, (u32*)Wxb, (u32*)Whb, hb, cb, bI, bU, bF);

    lp_gemm<<<2304, 256, 0, stream>>>(Xb, Wxb, bI, bU, hb, cb, pre);

    const int starts[8] = {5461, 1365, 341, 85, 21, 5, 1, 0};
    const int ends[8]   = {16384, 5461, 1365, 341, 85, 21, 5, 1};
    for (int l = 0; l < 8; ++l) {
        const int s = starts[l], e = ends[l];
        const int L = e - s;
        const int crow0 = 4 * s + 1;
        const int nIUrb = (L + 127) >> 7;
        const int nFrb  = (4 * L + 127) >> 7;
        rec_gemm<<<nIUrb * 4 + nFrb * 2, 256, 0, stream>>>(hb, hsb, Whb, pre, bF, cb,
            pIU, fc, s, crow0, L, (l == 0) ? 1 : 0);
        const int ng = (L + 3) >> 2;
        const int gateBlocks = (ng + 1) >> 1;
        const int hsBlocks = (l == 0) ? 683 : 0;
        gate_kernel<<<gateBlocks + hsBlocks, 256, 0, stream>>>(
            (const u32*)pre, (const u32*)pIU, fc, bI, bU,
            (u32*)hb, (u32*)cb, (u32*)hsb, out, s, L);
    }
}